// Round 2
// baseline (795.180 us; speedup 1.0000x reference)
//
#include <hip/hip_runtime.h>
#include <math.h>

#define HW_     (1024 * 1024)
#define NBATCH  4
#define NPIX    (NBATCH * HW_)          // 4,194,304 pixels
#define NG      (NPIX / 4)              // 1,048,576 float4 groups
#define NSETS   64
#define ACC_STRIDE 32                   // doubles/set: 0..7 sx, 8..15 sy, 16..23 cnt, 24 p1, 25 p3
#define GRID1   2048
#define BLOCK_  256
#define STRIDE1 (GRID1 * BLOCK_)        // 524,288 threads; 2 groups/thread

// ---- per-group (4 consecutive pixels): x_avg, y_avg, argmax label ----
__device__ __forceinline__ void compute_group(
    const float* __restrict__ x, const float* __restrict__ y,
    const float* __restrict__ mk, int g,
    float xa[4], float ya[4], int L[4])
{
    int p0 = g << 2;
    int b  = p0 >> 20;              // HW_ = 2^20
    int hw = p0 & (HW_ - 1);

    size_t xb = (size_t)(b * 3) * HW_ + hw;
    float4 x0 = *(const float4*)(x + xb);
    float4 x1 = *(const float4*)(x + xb + HW_);
    float4 x2 = *(const float4*)(x + xb + 2 * (size_t)HW_);
    float4 y0 = *(const float4*)(y + xb);
    float4 y1 = *(const float4*)(y + xb + HW_);
    float4 y2 = *(const float4*)(y + xb + 2 * (size_t)HW_);

    size_t mb = (size_t)(b * 8) * HW_ + hw;
    float4 m[8];
#pragma unroll
    for (int c = 0; c < 8; ++c) m[c] = *(const float4*)(mk + mb + (size_t)c * HW_);

    const float inv3 = 1.0f / 3.0f;     // mul, not the v_div_* sequence
    xa[0] = (x0.x + x1.x + x2.x) * inv3;
    xa[1] = (x0.y + x1.y + x2.y) * inv3;
    xa[2] = (x0.z + x1.z + x2.z) * inv3;
    xa[3] = (x0.w + x1.w + x2.w) * inv3;
    ya[0] = (y0.x + y1.x + y2.x) * inv3;
    ya[1] = (y0.y + y1.y + y2.y) * inv3;
    ya[2] = (y0.z + y1.z + y2.z) * inv3;
    ya[3] = (y0.w + y1.w + y2.w) * inv3;

    const float* mf = (const float*)m;
#pragma unroll
    for (int j = 0; j < 4; ++j) {
        float best = mf[j]; int bi = 0;
#pragma unroll
        for (int c = 1; c < 8; ++c) {
            float v = mf[c * 4 + j];
            if (v > best) { best = v; bi = c; }   // strict >: first occurrence (jnp.argmax)
        }
        L[j] = bi;
    }
}

__device__ __forceinline__ double acc_load(const double* p) {
    return __hip_atomic_load(p, __ATOMIC_RELAXED, __HIP_MEMORY_SCOPE_AGENT);
}

// ---- kernel A: per-label sums + stash + last-block finalize ----
template <bool STORE>
__global__ __launch_bounds__(256) void pass1_kernel(
    const float* __restrict__ x, const float* __restrict__ y,
    const float* __restrict__ mk, double* __restrict__ acc,
    float4* __restrict__ xavg, float4* __restrict__ yavg,
    unsigned* __restrict__ lab, double* __restrict__ fin,
    unsigned* __restrict__ cnt)
{
    int t = blockIdx.x * BLOCK_ + threadIdx.x;

    float xa0[4], ya0[4], xa1[4], ya1[4];
    int L0[4], L1[4];
    compute_group(x, y, mk, t,           xa0, ya0, L0);
    compute_group(x, y, mk, t + STRIDE1, xa1, ya1, L1);

    float sx[8], sy[8], sc[8];
#pragma unroll
    for (int l = 0; l < 8; ++l) { sx[l] = 0.f; sy[l] = 0.f; sc[l] = 0.f; }
#pragma unroll
    for (int j = 0; j < 4; ++j) {
#pragma unroll
        for (int l = 0; l < 8; ++l) {
            bool p0 = (L0[j] == l), p1 = (L1[j] == l);
            sx[l] += (p0 ? xa0[j] : 0.f) + (p1 ? xa1[j] : 0.f);
            sy[l] += (p0 ? ya0[j] : 0.f) + (p1 ? ya1[j] : 0.f);
            sc[l] += (p0 ? 1.f : 0.f) + (p1 ? 1.f : 0.f);
        }
    }
    if (STORE) {
        xavg[t] = make_float4(xa0[0], xa0[1], xa0[2], xa0[3]);
        yavg[t] = make_float4(ya0[0], ya0[1], ya0[2], ya0[3]);
        lab[t]  = (unsigned)L0[0] | ((unsigned)L0[1] << 8) |
                  ((unsigned)L0[2] << 16) | ((unsigned)L0[3] << 24);
        xavg[t + STRIDE1] = make_float4(xa1[0], xa1[1], xa1[2], xa1[3]);
        yavg[t + STRIDE1] = make_float4(ya1[0], ya1[1], ya1[2], ya1[3]);
        lab[t + STRIDE1]  = (unsigned)L1[0] | ((unsigned)L1[1] << 8) |
                            ((unsigned)L1[2] << 16) | ((unsigned)L1[3] << 24);
    }

#pragma unroll
    for (int l = 0; l < 8; ++l) {
#pragma unroll
        for (int off = 32; off > 0; off >>= 1) {
            sx[l] += __shfl_down(sx[l], off);
            sy[l] += __shfl_down(sy[l], off);
            sc[l] += __shfl_down(sc[l], off);
        }
    }
    __shared__ float red[4][24];
    int wave = threadIdx.x >> 6, lane = threadIdx.x & 63;
    if (lane == 0) {
#pragma unroll
        for (int l = 0; l < 8; ++l) {
            red[wave][l]      = sx[l];
            red[wave][8 + l]  = sy[l];
            red[wave][16 + l] = sc[l];
        }
    }
    __syncthreads();
    if (threadIdx.x < 24) {
        float v = red[0][threadIdx.x] + red[1][threadIdx.x] +
                  red[2][threadIdx.x] + red[3][threadIdx.x];
        atomicAdd(&acc[(blockIdx.x & (NSETS - 1)) * ACC_STRIDE + threadIdx.x],
                  (double)v);
    }
    __threadfence();
    __syncthreads();

    __shared__ int isLast;
    if (threadIdx.x == 0)
        isLast = (atomicAdd(cnt, 1u) == (unsigned)(gridDim.x - 1));
    __syncthreads();
    if (!isLast) return;

    // last block: finalize region averages + constant loss terms (f64)
    __shared__ double sh[24];
    if (threadIdx.x < 24) {
        double s = 0.0;
        for (int k = 0; k < NSETS; ++k)
            s += acc_load(&acc[k * ACC_STRIDE + threadIdx.x]);
        sh[threadIdx.x] = s;
    }
    __syncthreads();
    if (threadIdx.x == 0) {
        const double invN = 1.0 / (double)NPIX;
        double l2 = 0.0, l1c = 0.0;
        for (int l = 0; l < 8; ++l) {
            double XA  = sh[l] * invN;
            double YA  = sh[8 + l] * invN;
            double c   = sh[16 + l];
            double pw  = pow(XA, YA);
            l2  += pw;
            l1c += ((double)NPIX - c) * pw;
            fin[l]     = XA;
            fin[8 + l] = YA;
        }
        fin[16] = l1c;
        fin[17] = l2;
    }
}

// ---- kernel B: per-pixel pow + variance + last-block output ----
template <bool STORED>
__global__ __launch_bounds__(256) void pass2_kernel(
    const float4* __restrict__ xavg, const float4* __restrict__ yavg,
    const unsigned* __restrict__ lab,
    const float* __restrict__ x, const float* __restrict__ y,
    const float* __restrict__ mk,
    const double* __restrict__ fin, double* __restrict__ acc,
    unsigned* __restrict__ cnt, float* __restrict__ out)
{
    __shared__ float sXA[8], sYA[8];
    if (threadIdx.x < 8) {
        sXA[threadIdx.x] = (float)fin[threadIdx.x];
        sYA[threadIdx.x] = (float)fin[8 + threadIdx.x];
    }
    __syncthreads();

    int t = blockIdx.x * BLOCK_ + threadIdx.x;
    float p1 = 0.f, p3 = 0.f;
#pragma unroll
    for (int it = 0; it < 2; ++it) {
        int g = t + it * STRIDE1;
        float xa[4], ya[4]; int L[4];
        if (STORED) {
            float4 xv = xavg[g];
            float4 yv = yavg[g];
            unsigned lv = lab[g];
            xa[0] = xv.x; xa[1] = xv.y; xa[2] = xv.z; xa[3] = xv.w;
            ya[0] = yv.x; ya[1] = yv.y; ya[2] = yv.z; ya[3] = yv.w;
            L[0] = lv & 0xff; L[1] = (lv >> 8) & 0xff;
            L[2] = (lv >> 16) & 0xff; L[3] = (lv >> 24) & 0xff;
        } else {
            compute_group(x, y, mk, g, xa, ya, L);
        }
#pragma unroll
        for (int j = 0; j < 4; ++j) {
            int l = L[j];
            float XA = sXA[l], YA = sYA[l];
            float xr = (xa[j] != 0.0f) ? xa[j] : XA;   // refill semantics; xr>0
            float yr = (ya[j] != 0.0f) ? ya[j] : YA;
            p1 += exp2f(yr * __log2f(xr));             // fast HW transcendentals
            float d = xr - XA;
            p3 += d * d;
        }
    }

#pragma unroll
    for (int off = 32; off > 0; off >>= 1) {
        p1 += __shfl_down(p1, off);
        p3 += __shfl_down(p3, off);
    }
    __shared__ float r2[4][2];
    int wave = threadIdx.x >> 6, lane = threadIdx.x & 63;
    if (lane == 0) { r2[wave][0] = p1; r2[wave][1] = p3; }
    __syncthreads();
    if (threadIdx.x < 2) {
        float v = r2[0][threadIdx.x] + r2[1][threadIdx.x] +
                  r2[2][threadIdx.x] + r2[3][threadIdx.x];
        atomicAdd(&acc[(blockIdx.x & (NSETS - 1)) * ACC_STRIDE + 24 + threadIdx.x],
                  (double)v);
    }
    __threadfence();
    __syncthreads();

    __shared__ int isLast;
    if (threadIdx.x == 0)
        isLast = (atomicAdd(cnt, 1u) == (unsigned)(gridDim.x - 1));
    __syncthreads();
    if (!isLast) return;

    if (threadIdx.x == 0) {
        double s1 = 0.0, s3 = 0.0;
        for (int k = 0; k < NSETS; ++k) {
            s1 += acc_load(&acc[k * ACC_STRIDE + 24]);
            s3 += acc_load(&acc[k * ACC_STRIDE + 25]);
        }
        const double invN = 1.0 / (double)NPIX;
        out[0] = (float)((s1 + fin[16]) * invN);
        out[1] = (float)fin[17];
        out[2] = (float)(s3 * invN);
    }
}

extern "C" void kernel_launch(void* const* d_in, const int* in_sizes, int n_in,
                              void* d_out, int out_size, void* d_ws, size_t ws_size,
                              hipStream_t stream)
{
    const float* x  = (const float*)d_in[0];
    const float* y  = (const float*)d_in[1];
    const float* mk = (const float*)d_in[2];
    float* out = (float*)d_out;

    char* ws = (char*)d_ws;
    double*   acc  = (double*)ws;                        // [0, 16384): 64*32 doubles
    unsigned* cntA = (unsigned*)(ws + 16384);
    unsigned* cntB = (unsigned*)(ws + 16384 + 4);
    double*   fin  = (double*)(ws + 16640);              // 24 doubles
    char* arr = ws + 16896;                              // 16-B aligned
    float4*   xavg = (float4*)arr;
    float4*   yavg = (float4*)(arr + (size_t)NPIX * 4);
    unsigned* lab  = (unsigned*)(arr + (size_t)NPIX * 8);

    size_t need = 16896 + (size_t)NPIX * 9;
    bool stored = (ws_size >= need);

    hipMemsetAsync(ws, 0, 16640, stream);                // acc + counters

    if (stored) {
        pass1_kernel<true><<<GRID1, BLOCK_, 0, stream>>>(x, y, mk, acc, xavg, yavg,
                                                         lab, fin, cntA);
        pass2_kernel<true><<<GRID1, BLOCK_, 0, stream>>>(xavg, yavg, lab, x, y, mk,
                                                         fin, acc, cntB, out);
    } else {
        pass1_kernel<false><<<GRID1, BLOCK_, 0, stream>>>(x, y, mk, acc, xavg, yavg,
                                                          lab, fin, cntA);
        pass2_kernel<false><<<GRID1, BLOCK_, 0, stream>>>(xavg, yavg, lab, x, y, mk,
                                                          fin, acc, cntB, out);
    }
}

// Round 5
// 285.354 us; speedup vs baseline: 2.7866x; 2.7866x over previous
//
#include <hip/hip_runtime.h>
#include <math.h>

#define HW_     (1024 * 1024)
#define NBATCH  4
#define NPIX    (NBATCH * HW_)          // 4,194,304 pixels
#define NG      (NPIX / 4)              // 1,048,576 float4 groups
#define NSETS   64
#define ACC_STRIDE 32                   // doubles/set: 0..7 sx, 8..15 sy, 16..23 cnt, 24 p1, 25 p3
#define GRID1   2048
#define BLOCK_  256

// fast pow for x>0: v_log_f32 (log2) + v_mul + v_exp_f32 (exp2)
__device__ __forceinline__ float fast_pow_pos(float x, float p) {
    return __builtin_amdgcn_exp2f(p * __builtin_amdgcn_logf(x));
}

// ---- per-group (4 consecutive pixels): x_avg, y_avg, argmax label ----
__device__ __forceinline__ void compute_group(
    const float* __restrict__ x, const float* __restrict__ y,
    const float* __restrict__ mk, int g,
    float xa[4], float ya[4], int L[4])
{
    int p0 = g << 2;
    int b  = p0 >> 20;              // HW_ = 2^20
    int hw = p0 & (HW_ - 1);

    size_t xb = (size_t)(b * 3) * HW_ + hw;
    float4 x0 = *(const float4*)(x + xb);
    float4 x1 = *(const float4*)(x + xb + HW_);
    float4 x2 = *(const float4*)(x + xb + 2 * (size_t)HW_);
    float4 y0 = *(const float4*)(y + xb);
    float4 y1 = *(const float4*)(y + xb + HW_);
    float4 y2 = *(const float4*)(y + xb + 2 * (size_t)HW_);

    size_t mb = (size_t)(b * 8) * HW_ + hw;
    float4 m[8];
#pragma unroll
    for (int c = 0; c < 8; ++c) m[c] = *(const float4*)(mk + mb + (size_t)c * HW_);

    const float inv3 = 1.0f / 3.0f;     // mul, not the v_div_* sequence
    xa[0] = (x0.x + x1.x + x2.x) * inv3;
    xa[1] = (x0.y + x1.y + x2.y) * inv3;
    xa[2] = (x0.z + x1.z + x2.z) * inv3;
    xa[3] = (x0.w + x1.w + x2.w) * inv3;
    ya[0] = (y0.x + y1.x + y2.x) * inv3;
    ya[1] = (y0.y + y1.y + y2.y) * inv3;
    ya[2] = (y0.z + y1.z + y2.z) * inv3;
    ya[3] = (y0.w + y1.w + y2.w) * inv3;

    const float* mf = (const float*)m;
#pragma unroll
    for (int j = 0; j < 4; ++j) {
        float best = mf[j]; int bi = 0;
#pragma unroll
        for (int c = 1; c < 8; ++c) {
            float v = mf[c * 4 + j];
            if (v > best) { best = v; bi = c; }   // strict >: first occurrence (jnp.argmax)
        }
        L[j] = bi;
    }
}

// ---- pass 1: per-label sums (+optional stash of intermediates) ----
template <bool STORE>
__global__ __launch_bounds__(256) void pass1_kernel(
    const float* __restrict__ x, const float* __restrict__ y,
    const float* __restrict__ mk, double* __restrict__ acc,
    float4* __restrict__ xavg, float4* __restrict__ yavg,
    unsigned* __restrict__ lab)
{
    float sx[8], sy[8], sc[8];
#pragma unroll
    for (int l = 0; l < 8; ++l) { sx[l] = 0.f; sy[l] = 0.f; sc[l] = 0.f; }

    for (int g = blockIdx.x * blockDim.x + threadIdx.x; g < NG;
         g += gridDim.x * blockDim.x) {
        float xa[4], ya[4]; int L[4];
        compute_group(x, y, mk, g, xa, ya, L);
#pragma unroll
        for (int j = 0; j < 4; ++j) {
#pragma unroll
            for (int l = 0; l < 8; ++l) {
                bool p = (L[j] == l);
                sx[l] += p ? xa[j] : 0.0f;
                sy[l] += p ? ya[j] : 0.0f;
                sc[l] += p ? 1.0f : 0.0f;
            }
        }
        if (STORE) {
            xavg[g] = make_float4(xa[0], xa[1], xa[2], xa[3]);
            yavg[g] = make_float4(ya[0], ya[1], ya[2], ya[3]);
            lab[g]  = (unsigned)L[0] | ((unsigned)L[1] << 8) |
                      ((unsigned)L[2] << 16) | ((unsigned)L[3] << 24);
        }
    }

    // wave64 shuffle reduction of 24 accumulators
#pragma unroll
    for (int l = 0; l < 8; ++l) {
#pragma unroll
        for (int off = 32; off > 0; off >>= 1) {
            sx[l] += __shfl_down(sx[l], off);
            sy[l] += __shfl_down(sy[l], off);
            sc[l] += __shfl_down(sc[l], off);
        }
    }
    __shared__ float red[4][24];
    int wave = threadIdx.x >> 6, lane = threadIdx.x & 63;
    if (lane == 0) {
#pragma unroll
        for (int l = 0; l < 8; ++l) {
            red[wave][l]      = sx[l];
            red[wave][8 + l]  = sy[l];
            red[wave][16 + l] = sc[l];
        }
    }
    __syncthreads();
    if (threadIdx.x < 24) {
        float t = red[0][threadIdx.x] + red[1][threadIdx.x] +
                  red[2][threadIdx.x] + red[3][threadIdx.x];
        atomicAdd(&acc[(blockIdx.x & (NSETS - 1)) * ACC_STRIDE + threadIdx.x],
                  (double)t);
    }
}

// ---- finalize 1: region averages + constant loss terms (f64) ----
__global__ void finalize1_kernel(const double* __restrict__ acc,
                                 double* __restrict__ fin)
{
    __shared__ double sh[24];
    int t = threadIdx.x;
    if (t < 24) {
        double s = 0.0;
        for (int k = 0; k < NSETS; ++k) s += acc[k * ACC_STRIDE + t];
        sh[t] = s;
    }
    __syncthreads();
    if (t == 0) {
        const double invN = 1.0 / (double)NPIX;
        double l2 = 0.0, l1c = 0.0;
        for (int l = 0; l < 8; ++l) {
            double XA  = sh[l] * invN;
            double YA  = sh[8 + l] * invN;
            double cnt = sh[16 + l];
            double pw  = pow(XA, YA);       // pow(0,0)=1 matches jnp/np
            l2  += pw;
            l1c += ((double)NPIX - cnt) * pw;
            fin[l]     = XA;
            fin[8 + l] = YA;
        }
        fin[16] = l1c;
        fin[17] = l2;
    }
}

// ---- pass 2: per-pixel pow + variance sums ----
template <bool STORED>
__global__ __launch_bounds__(256) void pass2_kernel(
    const float4* __restrict__ xavg, const float4* __restrict__ yavg,
    const unsigned* __restrict__ lab,
    const float* __restrict__ x, const float* __restrict__ y,
    const float* __restrict__ mk,
    const double* __restrict__ fin, double* __restrict__ acc)
{
    __shared__ float sXA[8], sYA[8];
    if (threadIdx.x < 8) {
        sXA[threadIdx.x] = (float)fin[threadIdx.x];
        sYA[threadIdx.x] = (float)fin[8 + threadIdx.x];
    }
    __syncthreads();

    float p1 = 0.f, p3 = 0.f;
    for (int g = blockIdx.x * blockDim.x + threadIdx.x; g < NG;
         g += gridDim.x * blockDim.x) {
        float xa[4], ya[4]; int L[4];
        if (STORED) {
            float4 xv = xavg[g];
            float4 yv = yavg[g];
            unsigned lv = lab[g];
            xa[0] = xv.x; xa[1] = xv.y; xa[2] = xv.z; xa[3] = xv.w;
            ya[0] = yv.x; ya[1] = yv.y; ya[2] = yv.z; ya[3] = yv.w;
            L[0] = lv & 0xff; L[1] = (lv >> 8) & 0xff;
            L[2] = (lv >> 16) & 0xff; L[3] = (lv >> 24) & 0xff;
        } else {
            compute_group(x, y, mk, g, xa, ya, L);
        }
#pragma unroll
        for (int j = 0; j < 4; ++j) {
            int l = L[j];
            float XA = sXA[l], YA = sYA[l];
            float xr = (xa[j] != 0.0f) ? xa[j] : XA;   // refill semantics; xr > 0
            float yr = (ya[j] != 0.0f) ? ya[j] : YA;
            p1 += fast_pow_pos(xr, yr);
            float d = xr - XA;
            p3 += d * d;
        }
    }

#pragma unroll
    for (int off = 32; off > 0; off >>= 1) {
        p1 += __shfl_down(p1, off);
        p3 += __shfl_down(p3, off);
    }
    __shared__ float r2[4][2];
    int wave = threadIdx.x >> 6, lane = threadIdx.x & 63;
    if (lane == 0) { r2[wave][0] = p1; r2[wave][1] = p3; }
    __syncthreads();
    if (threadIdx.x < 2) {
        float t = r2[0][threadIdx.x] + r2[1][threadIdx.x] +
                  r2[2][threadIdx.x] + r2[3][threadIdx.x];
        atomicAdd(&acc[(blockIdx.x & (NSETS - 1)) * ACC_STRIDE + 24 + threadIdx.x],
                  (double)t);
    }
}

// ---- finalize 2: write the 3 scalar outputs ----
__global__ void finalize2_kernel(const double* __restrict__ acc,
                                 const double* __restrict__ fin,
                                 float* __restrict__ out)
{
    if (threadIdx.x == 0 && blockIdx.x == 0) {
        double p1 = 0.0, p3 = 0.0;
        for (int k = 0; k < NSETS; ++k) {
            p1 += acc[k * ACC_STRIDE + 24];
            p3 += acc[k * ACC_STRIDE + 25];
        }
        const double invN = 1.0 / (double)NPIX;
        out[0] = (float)((p1 + fin[16]) * invN);
        out[1] = (float)fin[17];
        out[2] = (float)(p3 * invN);
    }
}

extern "C" void kernel_launch(void* const* d_in, const int* in_sizes, int n_in,
                              void* d_out, int out_size, void* d_ws, size_t ws_size,
                              hipStream_t stream)
{
    const float* x  = (const float*)d_in[0];
    const float* y  = (const float*)d_in[1];
    const float* mk = (const float*)d_in[2];
    float* out = (float*)d_out;

    char* ws = (char*)d_ws;
    double* acc = (double*)ws;                                  // 64*32*8 = 16 KB
    double* fin = (double*)(ws + NSETS * ACC_STRIDE * 8);       // 24 doubles
    char* arr = ws + NSETS * ACC_STRIDE * 8 + 256;              // 16-B aligned
    float4*   xavg = (float4*)arr;
    float4*   yavg = (float4*)(arr + (size_t)NPIX * 4);
    unsigned* lab  = (unsigned*)(arr + (size_t)NPIX * 8);

    size_t need = (size_t)(NSETS * ACC_STRIDE * 8 + 256) + (size_t)NPIX * 9;
    bool stored = (ws_size >= need);

    (void)hipMemsetAsync(acc, 0, NSETS * ACC_STRIDE * 8, stream);

    if (stored) {
        pass1_kernel<true><<<GRID1, BLOCK_, 0, stream>>>(x, y, mk, acc, xavg, yavg, lab);
        finalize1_kernel<<<1, 64, 0, stream>>>(acc, fin);
        pass2_kernel<true><<<GRID1, BLOCK_, 0, stream>>>(xavg, yavg, lab, x, y, mk, fin, acc);
    } else {
        pass1_kernel<false><<<GRID1, BLOCK_, 0, stream>>>(x, y, mk, acc, xavg, yavg, lab);
        finalize1_kernel<<<1, 64, 0, stream>>>(acc, fin);
        pass2_kernel<false><<<GRID1, BLOCK_, 0, stream>>>(xavg, yavg, lab, x, y, mk, fin, acc);
    }
    finalize2_kernel<<<1, 1, 0, stream>>>(acc, fin, out);
}

// Round 6
// 269.787 us; speedup vs baseline: 2.9474x; 1.0577x over previous
//
#include <hip/hip_runtime.h>
#include <math.h>

#define HW_     (1024 * 1024)
#define NBATCH  4
#define NPIX    (NBATCH * HW_)          // 4,194,304 pixels
#define NG      (NPIX / 4)              // 1,048,576 float4 groups
#define NSETS   64
#define ACC_STRIDE 32                   // doubles/set: 0..7 sx, 8..15 sy, 16..23 cnt, 24 spw, 25 sxx
#define GRID1   2048
#define BLOCK_  256

// fast pow for x>0: v_log_f32 (log2) + v_mul + v_exp_f32 (exp2)
__device__ __forceinline__ float fast_pow_pos(float x, float p) {
    return __builtin_amdgcn_exp2f(p * __builtin_amdgcn_logf(x));
}

// ---- per-group (4 consecutive pixels): x_avg, y_avg, argmax label ----
__device__ __forceinline__ void compute_group(
    const float* __restrict__ x, const float* __restrict__ y,
    const float* __restrict__ mk, int g,
    float xa[4], float ya[4], int L[4])
{
    int p0 = g << 2;
    int b  = p0 >> 20;              // HW_ = 2^20
    int hw = p0 & (HW_ - 1);

    size_t xb = (size_t)(b * 3) * HW_ + hw;
    float4 x0 = *(const float4*)(x + xb);
    float4 x1 = *(const float4*)(x + xb + HW_);
    float4 x2 = *(const float4*)(x + xb + 2 * (size_t)HW_);
    float4 y0 = *(const float4*)(y + xb);
    float4 y1 = *(const float4*)(y + xb + HW_);
    float4 y2 = *(const float4*)(y + xb + 2 * (size_t)HW_);

    size_t mb = (size_t)(b * 8) * HW_ + hw;
    float4 m[8];
#pragma unroll
    for (int c = 0; c < 8; ++c) m[c] = *(const float4*)(mk + mb + (size_t)c * HW_);

    const float inv3 = 1.0f / 3.0f;     // mul, not the v_div_* sequence
    xa[0] = (x0.x + x1.x + x2.x) * inv3;
    xa[1] = (x0.y + x1.y + x2.y) * inv3;
    xa[2] = (x0.z + x1.z + x2.z) * inv3;
    xa[3] = (x0.w + x1.w + x2.w) * inv3;
    ya[0] = (y0.x + y1.x + y2.x) * inv3;
    ya[1] = (y0.y + y1.y + y2.y) * inv3;
    ya[2] = (y0.z + y1.z + y2.z) * inv3;
    ya[3] = (y0.w + y1.w + y2.w) * inv3;

    const float* mf = (const float*)m;
#pragma unroll
    for (int j = 0; j < 4; ++j) {
        float best = mf[j]; int bi = 0;
#pragma unroll
        for (int c = 1; c < 8; ++c) {
            float v = mf[c * 4 + j];
            if (v > best) { best = v; bi = c; }   // strict >: first occurrence (jnp.argmax)
        }
        L[j] = bi;
    }
}

// ---- single pass: per-label {sx,sy,cnt} + global {sum pow(xa,ya), sum xa^2} ----
__global__ __launch_bounds__(256) void pass1_kernel(
    const float* __restrict__ x, const float* __restrict__ y,
    const float* __restrict__ mk, double* __restrict__ acc)
{
    float sx[8], sy[8], sc[8];
#pragma unroll
    for (int l = 0; l < 8; ++l) { sx[l] = 0.f; sy[l] = 0.f; sc[l] = 0.f; }
    float spw = 0.f, sxx = 0.f;

    for (int g = blockIdx.x * blockDim.x + threadIdx.x; g < NG;
         g += gridDim.x * blockDim.x) {
        float xa[4], ya[4]; int L[4];
        compute_group(x, y, mk, g, xa, ya, L);
#pragma unroll
        for (int j = 0; j < 4; ++j) {
#pragma unroll
            for (int l = 0; l < 8; ++l) {
                bool p = (L[j] == l);
                sx[l] += p ? xa[j] : 0.0f;
                sy[l] += p ? ya[j] : 0.0f;
                sc[l] += p ? 1.0f : 0.0f;
            }
            spw += fast_pow_pos(xa[j], ya[j]);  // xa>0 (mean of uniforms)
            sxx += xa[j] * xa[j];
        }
    }

    // wave64 shuffle reduction of 26 accumulators
#pragma unroll
    for (int off = 32; off > 0; off >>= 1) {
#pragma unroll
        for (int l = 0; l < 8; ++l) {
            sx[l] += __shfl_down(sx[l], off);
            sy[l] += __shfl_down(sy[l], off);
            sc[l] += __shfl_down(sc[l], off);
        }
        spw += __shfl_down(spw, off);
        sxx += __shfl_down(sxx, off);
    }
    __shared__ float red[4][26];
    int wave = threadIdx.x >> 6, lane = threadIdx.x & 63;
    if (lane == 0) {
#pragma unroll
        for (int l = 0; l < 8; ++l) {
            red[wave][l]      = sx[l];
            red[wave][8 + l]  = sy[l];
            red[wave][16 + l] = sc[l];
        }
        red[wave][24] = spw;
        red[wave][25] = sxx;
    }
    __syncthreads();
    if (threadIdx.x < 26) {
        float t = red[0][threadIdx.x] + red[1][threadIdx.x] +
                  red[2][threadIdx.x] + red[3][threadIdx.x];
        atomicAdd(&acc[(blockIdx.x & (NSETS - 1)) * ACC_STRIDE + threadIdx.x],
                  (double)t);
    }
}

// ---- finalize: all three losses in f64, write 3 floats ----
__global__ void finalize_kernel(const double* __restrict__ acc,
                                float* __restrict__ out)
{
    __shared__ double sh[26];
    int t = threadIdx.x;
    if (t < 26) {
        double s = 0.0;
        for (int k = 0; k < NSETS; ++k) s += acc[k * ACC_STRIDE + t];
        sh[t] = s;
    }
    __syncthreads();
    if (t == 0) {
        const double invN = 1.0 / (double)NPIX;
        double l1 = sh[24];       // sum of pow over on-mask pixels
        double l3 = sh[25];       // sum of xa^2
        double l2 = 0.0;
        for (int l = 0; l < 8; ++l) {
            double SX  = sh[l];
            double XA  = SX * invN;
            double YA  = sh[8 + l] * invN;
            double cnt = sh[16 + l];
            double pw  = pow(XA, YA);
            l2 += pw;
            l1 += ((double)NPIX - cnt) * pw;          // off-mask pow terms
            l3 += cnt * XA * XA - 2.0 * XA * SX;      // per-label variance cross terms
        }
        out[0] = (float)(l1 * invN);
        out[1] = (float)l2;
        out[2] = (float)(l3 * invN);
    }
}

extern "C" void kernel_launch(void* const* d_in, const int* in_sizes, int n_in,
                              void* d_out, int out_size, void* d_ws, size_t ws_size,
                              hipStream_t stream)
{
    const float* x  = (const float*)d_in[0];
    const float* y  = (const float*)d_in[1];
    const float* mk = (const float*)d_in[2];
    float* out = (float*)d_out;

    double* acc = (double*)d_ws;                    // 64*32*8 = 16 KB
    (void)hipMemsetAsync(acc, 0, NSETS * ACC_STRIDE * 8, stream);

    pass1_kernel<<<GRID1, BLOCK_, 0, stream>>>(x, y, mk, acc);
    finalize_kernel<<<1, 64, 0, stream>>>(acc, out);
}